// Round 2
// baseline (495.335 us; speedup 1.0000x reference)
//
#include <hip/hip_runtime.h>

typedef unsigned short u16;
typedef float f4v __attribute__((ext_vector_type(4)));
typedef short s8v __attribute__((ext_vector_type(8)));
typedef int   i4v __attribute__((ext_vector_type(4)));

#define SCALE_ 0.08838834764831845f

__device__ __forceinline__ u16 f2b(float f) {
    union { float f; unsigned u; } c; c.f = f;
    unsigned u = c.u + 0x7fffu + ((c.u >> 16) & 1u);
    return (u16)(u >> 16);
}

// ---------------------------------------------------------------------------
// GEMM: C[m][n] = sum_k A[m][k] * B[n][k]   (B^T layout, both row-major)
// ---------------------------------------------------------------------------
template <int ABF16>
__global__ __launch_bounds__(256) void fgemm_bt(const void* __restrict__ Ap,
                                                const float* __restrict__ Bp,
                                                float* __restrict__ Cp,
                                                int M, int N, int K) {
    __shared__ __align__(16) char At[64 * 128];
    __shared__ __align__(16) char Bt[128 * 128];
    const int tid = threadIdx.x, lane = tid & 63, wid = tid >> 6;
    const int lm = lane & 15, lg = lane >> 4;
    const int m0 = blockIdx.y * 64, n0 = blockIdx.x * 128;
    const int NT = K >> 6;

    f4v acc[4][2];
#pragma unroll
    for (int mi = 0; mi < 4; mi++)
#pragma unroll
        for (int ni = 0; ni < 2; ni++) acc[mi][ni] = (f4v){0.f, 0.f, 0.f, 0.f};

    float fA[2][8];
    s8v   hA[2];
    float fB[4][8];

    auto loadT = [&](int kt) {
#pragma unroll
        for (int i = 0; i < 2; i++) {
            int c = tid + i * 256; int r = c >> 3, k8 = c & 7;
            if constexpr (ABF16) {
                hA[i] = *(const s8v*)((const u16*)Ap + (size_t)(m0 + r) * K + kt * 64 + k8 * 8);
            } else {
                const float* p = (const float*)Ap + (size_t)(m0 + r) * K + kt * 64 + k8 * 8;
                float4 u = *(const float4*)p, v = *(const float4*)(p + 4);
                fA[i][0] = u.x; fA[i][1] = u.y; fA[i][2] = u.z; fA[i][3] = u.w;
                fA[i][4] = v.x; fA[i][5] = v.y; fA[i][6] = v.z; fA[i][7] = v.w;
            }
        }
#pragma unroll
        for (int i = 0; i < 4; i++) {
            int c = tid + i * 256; int r = c >> 3, k8 = c & 7;
            const float* p = Bp + (size_t)(n0 + r) * K + kt * 64 + k8 * 8;
            float4 u = *(const float4*)p, v = *(const float4*)(p + 4);
            fB[i][0] = u.x; fB[i][1] = u.y; fB[i][2] = u.z; fB[i][3] = u.w;
            fB[i][4] = v.x; fB[i][5] = v.y; fB[i][6] = v.z; fB[i][7] = v.w;
        }
    };

    auto storeLDS = [&]() {
#pragma unroll
        for (int i = 0; i < 2; i++) {
            int c = tid + i * 256; int r = c >> 3, k8 = c & 7;
            s8v hv;
            if constexpr (ABF16) hv = hA[i];
            else {
#pragma unroll
                for (int j = 0; j < 8; j++) hv[j] = (short)f2b(fA[i][j]);
            }
            *(s8v*)(At + ((r * 128 + k8 * 16) ^ ((r & 7) << 4))) = hv;
        }
#pragma unroll
        for (int i = 0; i < 4; i++) {
            int c = tid + i * 256; int r = c >> 3, k8 = c & 7;
            s8v hv;
#pragma unroll
            for (int j = 0; j < 8; j++) hv[j] = (short)f2b(fB[i][j]);
            *(s8v*)(Bt + ((r * 128 + k8 * 16) ^ ((r & 7) << 4))) = hv;
        }
    };

    loadT(0);
    for (int kt = 0; kt < NT; ++kt) {
        __syncthreads();
        storeLDS();
        __syncthreads();
        if (kt + 1 < NT) loadT(kt + 1);
#pragma unroll
        for (int ks = 0; ks < 2; ks++) {
            s8v av[4], bv[2];
#pragma unroll
            for (int mi = 0; mi < 4; mi++) {
                int r = mi * 16 + lm;
                av[mi] = *(const s8v*)(At + ((r * 128 + ks * 64 + lg * 16) ^ ((r & 7) << 4)));
            }
#pragma unroll
            for (int ni = 0; ni < 2; ni++) {
                int r = wid * 32 + ni * 16 + lm;
                bv[ni] = *(const s8v*)(Bt + ((r * 128 + ks * 64 + lg * 16) ^ ((r & 7) << 4)));
            }
#pragma unroll
            for (int mi = 0; mi < 4; mi++)
#pragma unroll
                for (int ni = 0; ni < 2; ni++)
                    acc[mi][ni] = __builtin_amdgcn_mfma_f32_16x16x32_bf16(av[mi], bv[ni], acc[mi][ni], 0, 0, 0);
        }
    }

#pragma unroll
    for (int mi = 0; mi < 4; mi++)
#pragma unroll
        for (int ni = 0; ni < 2; ni++)
#pragma unroll
            for (int r = 0; r < 4; r++) {
                int m = m0 + mi * 16 + lg * 4 + r;
                int n = n0 + wid * 32 + ni * 16 + lm;
                Cp[(size_t)m * N + n] = acc[mi][ni][r];
            }
}

// ---------------------------------------------------------------------------
// Fused RMSNorm + RoPE + scale + bf16 convert.
// ---------------------------------------------------------------------------
__global__ __launch_bounds__(256) void nrope_k(const float* __restrict__ src,
                                               u16* __restrict__ dst,
                                               const float* __restrict__ w,
                                               const int* __restrict__ cseq,
                                               int nheads, float oscale) {
    const int lane = threadIdx.x & 63;
    const int rid = blockIdx.x * 4 + (threadIdx.x >> 6);
    const int s = (rid / nheads) & 127;
    const int b = rid / (nheads * 128);
    const float* p = src + (size_t)rid * 128;
    float x1 = p[lane], x2 = p[lane + 64];
    float ss = x1 * x1 + x2 * x2;
#pragma unroll
    for (int off = 1; off < 64; off <<= 1) ss += __shfl_xor(ss, off);
    float inv = rsqrtf(ss * (1.0f / 128.0f) + 1e-6f);
    float n1 = x1 * inv * w[lane];
    float n2 = x2 * inv * w[lane + 64];
    float pos = (float)(cseq[b] + s);
    float ang = pos * powf(10000.0f, -(float)lane * (1.0f / 64.0f));
    float cs = cosf(ang), sn = sinf(ang);
    dst[(size_t)rid * 128 + lane]      = f2b((n1 * cs - n2 * sn) * oscale);
    dst[(size_t)rid * 128 + lane + 64] = f2b((n2 * cs + n1 * sn) * oscale);
}

__global__ __launch_bounds__(256) void cvt_bf16k(const float* __restrict__ s,
                                                 u16* __restrict__ d, int n4) {
    int i = blockIdx.x * blockDim.x + threadIdx.x;
    if (i < n4) {
        float4 f = ((const float4*)s)[i];
        ushort4 o;
        o.x = f2b(f.x); o.y = f2b(f.y); o.z = f2b(f.z); o.w = f2b(f.w);
        ((ushort4*)d)[i] = o;
    }
}

// ---------------------------------------------------------------------------
// Flash attention, flash-decoding split-4.
// Block = (b, h, half, split): 1024 blocks, 4 waves x 16 q-rows, KV tile 64.
// K LDS: row-major swizzled. V LDS: k-pair-interleaved (dword = {V[2p][n],
// V[2p+1][n]}, 512B pair-rows, 16B-chunk XOR swizzle) -> PV B-frag = 4x b32.
// Partials (acc fp32, m, l) to ws; fcomb_k merges.
// ---------------------------------------------------------------------------
__global__ __launch_bounds__(256) void fattn_k(const u16* __restrict__ qb,
                                               const u16* __restrict__ kb,
                                               const u16* __restrict__ vb,
                                               const float* __restrict__ kc,
                                               const float* __restrict__ vc,
                                               const int* __restrict__ btab,
                                               const int* __restrict__ cseq,
                                               float* __restrict__ po,
                                               float* __restrict__ mb,
                                               float* __restrict__ lb) {
    __shared__ __align__(16) char Ks[64 * 256];
    __shared__ __align__(16) char Vs[32 * 512];
    __shared__ __align__(16) char Ps[4][2048];

    const int tid = threadIdx.x, lane = tid & 63, wid = tid >> 6;
    const int lm = lane & 15, lg = lane >> 4;
    const int bid = blockIdx.x;
    const int sp = bid & 3, half = (bid >> 2) & 1, h = (bid >> 3) & 31, b = bid >> 8;
    const int hk = h >> 2;

    s8v qa[4];
    {
        const u16* qp = qb + ((size_t)((b * 128 + half * 64 + wid * 16 + lm) * 32 + h)) * 128 + lg * 8;
#pragma unroll
        for (int ks = 0; ks < 4; ks++) qa[ks] = *(const s8v*)(qp + ks * 32);
    }

    float m_run[4], l_run[4];
    f4v acc[8];
#pragma unroll
    for (int r = 0; r < 4; r++) { m_run[r] = -1e30f; l_run[r] = 0.f; }
#pragma unroll
    for (int dt = 0; dt < 8; dt++) acc[dt] = (f4v){0.f, 0.f, 0.f, 0.f};

    const int cl = cseq[b];
    const int ntc = (cl + 63) >> 6;
    const int tlo = (ntc * sp) >> 2, thi = (ntc * (sp + 1)) >> 2;
    const int ncache = thi - tlo;
    const int ntiles = ncache + (sp == 3 ? 2 : 0);

    for (int ii = 0; ii < ntiles; ++ii) {
        const bool isnew = ii >= ncache;
        const int t0 = isnew ? (4096 + (ii - ncache) * 64) : (tlo + ii) * 64;
        __syncthreads();

        if (!isnew) {
            // ---- issue all K+V global loads, then convert+write ----
            f4v kr[4][2];
#pragma unroll
            for (int i = 0; i < 4; i++) {
                int c = tid + i * 256; int r = c >> 4, d8 = c & 15;
                int p = t0 + r;
                const float* src = kc + (((size_t)btab[b * 16 + (p >> 8)] * 256 + (p & 255)) * 8 + hk) * 128 + d8 * 8;
                kr[i][0] = *(const f4v*)src; kr[i][1] = *(const f4v*)(src + 4);
            }
            f4v vr[2][4];
#pragma unroll
            for (int i = 0; i < 2; i++) {
                int c = tid + i * 256; int pr = c >> 4, d8 = c & 15, n0 = d8 * 8;
                int prow = t0 + pr * 2;
                const float* src = vc + (((size_t)btab[b * 16 + (prow >> 8)] * 256 + (prow & 255)) * 8 + hk) * 128 + n0;
                vr[i][0] = *(const f4v*)src;          vr[i][1] = *(const f4v*)(src + 4);
                vr[i][2] = *(const f4v*)(src + 1024); vr[i][3] = *(const f4v*)(src + 1028);
            }
#pragma unroll
            for (int i = 0; i < 4; i++) {
                int c = tid + i * 256; int r = c >> 4, d8 = c & 15;
                s8v v;
#pragma unroll
                for (int j = 0; j < 4; j++) { v[j] = (short)f2b(kr[i][0][j]); v[j + 4] = (short)f2b(kr[i][1][j]); }
                *(s8v*)(Ks + ((r * 256 + d8 * 16) ^ ((r & 7) << 4))) = v;
            }
#pragma unroll
            for (int i = 0; i < 2; i++) {
                int c = tid + i * 256; int pr = c >> 4, d8 = c & 15, n0 = d8 * 8;
                i4v w1, w2;
#pragma unroll
                for (int j = 0; j < 4; j++) {
                    w1[j] = (int)((unsigned)f2b(vr[i][0][j]) | ((unsigned)f2b(vr[i][2][j]) << 16));
                    w2[j] = (int)((unsigned)f2b(vr[i][1][j]) | ((unsigned)f2b(vr[i][3][j]) << 16));
                }
                int swz = (pr & 31) << 4;
                *(i4v*)(Vs + pr * 512 + ((n0 * 4) ^ swz))      = w1;
                *(i4v*)(Vs + pr * 512 + ((n0 * 4 + 16) ^ swz)) = w2;
            }
        } else {
            int s0 = t0 - 4096;
            s8v kr2[4];
#pragma unroll
            for (int i = 0; i < 4; i++) {
                int c = tid + i * 256; int r = c >> 4, d8 = c & 15;
                kr2[i] = *(const s8v*)(kb + ((size_t)(b * 128 + s0 + r) * 8 + hk) * 128 + d8 * 8);
            }
            s8v vre[2], vro[2];
#pragma unroll
            for (int i = 0; i < 2; i++) {
                int c = tid + i * 256; int pr = c >> 4, d8 = c & 15, n0 = d8 * 8;
                const u16* src = vb + ((size_t)(b * 128 + s0 + pr * 2) * 8 + hk) * 128 + n0;
                vre[i] = *(const s8v*)src;
                vro[i] = *(const s8v*)(src + 1024);
            }
#pragma unroll
            for (int i = 0; i < 4; i++) {
                int c = tid + i * 256; int r = c >> 4, d8 = c & 15;
                *(s8v*)(Ks + ((r * 256 + d8 * 16) ^ ((r & 7) << 4))) = kr2[i];
            }
#pragma unroll
            for (int i = 0; i < 2; i++) {
                int c = tid + i * 256; int pr = c >> 4, d8 = c & 15, n0 = d8 * 8;
                i4v w1, w2;
#pragma unroll
                for (int j = 0; j < 4; j++) {
                    w1[j] = (int)((unsigned)(u16)vre[i][j] | ((unsigned)(u16)vro[i][j] << 16));
                    w2[j] = (int)((unsigned)(u16)vre[i][j + 4] | ((unsigned)(u16)vro[i][j + 4] << 16));
                }
                int swz = (pr & 31) << 4;
                *(i4v*)(Vs + pr * 512 + ((n0 * 4) ^ swz))      = w1;
                *(i4v*)(Vs + pr * 512 + ((n0 * 4 + 16) ^ swz)) = w2;
            }
        }
        __syncthreads();

        // ---- Q @ K^T ----
        f4v sc[4];
#pragma unroll
        for (int ct = 0; ct < 4; ct++) sc[ct] = (f4v){0.f, 0.f, 0.f, 0.f};
#pragma unroll
        for (int ct = 0; ct < 4; ct++) {
#pragma unroll
            for (int ks = 0; ks < 4; ks++) {
                int r = ct * 16 + lm;
                s8v kf = *(const s8v*)(Ks + ((r * 256 + ks * 64 + lg * 16) ^ ((r & 7) << 4)));
                sc[ct] = __builtin_amdgcn_mfma_f32_16x16x32_bf16(qa[ks], kf, sc[ct], 0, 0, 0);
            }
        }
        if (!isnew && (t0 + 64 > cl)) {
#pragma unroll
            for (int ct = 0; ct < 4; ct++) {
                int p = t0 + ct * 16 + lm;
                if (p >= cl) { sc[ct][0] = -1e30f; sc[ct][1] = -1e30f; sc[ct][2] = -1e30f; sc[ct][3] = -1e30f; }
            }
        }

        // ---- online softmax ----
        float mnew[4], corr[4], rsum[4];
#pragma unroll
        for (int r = 0; r < 4; r++) {
            float mt = fmaxf(fmaxf(sc[0][r], sc[1][r]), fmaxf(sc[2][r], sc[3][r]));
#pragma unroll
            for (int off = 1; off < 16; off <<= 1) mt = fmaxf(mt, __shfl_xor(mt, off));
            float mn = fmaxf(m_run[r], mt);
            corr[r] = __expf(m_run[r] - mn);
            m_run[r] = mn;
            mnew[r] = mn;
            rsum[r] = 0.f;
        }
#pragma unroll
        for (int ct = 0; ct < 4; ct++) {
#pragma unroll
            for (int r = 0; r < 4; r++) {
                float pv = __expf(sc[ct][r] - mnew[r]);
                rsum[r] += pv;
                int row = lg * 4 + r;
                *(u16*)(Ps[wid] + ((row * 128 + (ct * 16 + lm) * 2) ^ ((row & 7) << 4))) = f2b(pv);
            }
        }
#pragma unroll
        for (int r = 0; r < 4; r++) {
            float rs = rsum[r];
#pragma unroll
            for (int off = 1; off < 16; off <<= 1) rs += __shfl_xor(rs, off);
            l_run[r] = l_run[r] * corr[r] + rs;
        }
#pragma unroll
        for (int dt = 0; dt < 8; dt++) {
#pragma unroll
            for (int r = 0; r < 4; r++) acc[dt][r] *= corr[r];
        }

        // ---- P A-frags from per-wave LDS ----
        s8v pa[2];
#pragma unroll
        for (int k2 = 0; k2 < 2; k2++)
            pa[k2] = *(const s8v*)(Ps[wid] + ((lm * 128 + k2 * 64 + lg * 16) ^ ((lm & 7) << 4)));

        // ---- P @ V from LDS (pair-interleaved b32 reads) ----
#pragma unroll
        for (int k2 = 0; k2 < 2; k2++) {
#pragma unroll
            for (int dt = 0; dt < 8; dt++) {
                i4v vv;
#pragma unroll
                for (int t = 0; t < 4; t++) {
                    int p = k2 * 16 + lg * 4 + t;
                    vv[t] = *(const int*)(Vs + p * 512 + ((((dt * 16 + lm) * 4)) ^ ((p & 31) << 4)));
                }
                union { i4v i; s8v s; } u; u.i = vv;
                acc[dt] = __builtin_amdgcn_mfma_f32_16x16x32_bf16(pa[k2], u.s, acc[dt], 0, 0, 0);
            }
        }
    }

    // ---- write partials ----
#pragma unroll
    for (int dt = 0; dt < 8; dt++) {
#pragma unroll
        for (int r = 0; r < 4; r++) {
            int row = wid * 16 + lg * 4 + r;
            po[((size_t)bid * 64 + row) * 128 + dt * 16 + lm] = acc[dt][r];
        }
    }
    if (lm == 0) {
#pragma unroll
        for (int r = 0; r < 4; r++) {
            int row = wid * 16 + lg * 4 + r;
            mb[(size_t)bid * 64 + row] = m_run[r];
            lb[(size_t)bid * 64 + row] = l_run[r];
        }
    }
}

// ---------------------------------------------------------------------------
// Combine 4 splits: O = (sum_i e^{m_i-M} acc_i) / (sum_i e^{m_i-M} l_i)
// ---------------------------------------------------------------------------
__global__ __launch_bounds__(256) void fcomb_k(const float* __restrict__ po,
                                               const float* __restrict__ mb,
                                               const float* __restrict__ lb,
                                               u16* __restrict__ ob) {
    const int pid = blockIdx.x, t = threadIdx.x;
    const int row = t >> 2, dq = t & 3;
    const int half = pid & 1, h = (pid >> 1) & 31, b = pid >> 6;
    float m[4], l[4];
#pragma unroll
    for (int i = 0; i < 4; i++) {
        m[i] = mb[(size_t)(pid * 4 + i) * 64 + row];
        l[i] = lb[(size_t)(pid * 4 + i) * 64 + row];
    }
    float M = fmaxf(fmaxf(m[0], m[1]), fmaxf(m[2], m[3]));
    float w[4], L = 0.f;
#pragma unroll
    for (int i = 0; i < 4; i++) { w[i] = __expf(m[i] - M); L += w[i] * l[i]; }
    float invL = 1.0f / L;
    u16* dst = ob + ((size_t)(b * 128 + half * 64 + row) * 32 + h) * 128 + dq * 32;
#pragma unroll
    for (int j = 0; j < 8; j++) {
        f4v s = (f4v){0.f, 0.f, 0.f, 0.f};
#pragma unroll
        for (int i = 0; i < 4; i++) {
            f4v a = *(const f4v*)(po + ((size_t)(pid * 4 + i) * 64 + row) * 128 + dq * 32 + j * 4);
            s += w[i] * a;
        }
        ushort4 o;
        o.x = f2b(s[0] * invL); o.y = f2b(s[1] * invL);
        o.z = f2b(s[2] * invL); o.w = f2b(s[3] * invL);
        *(ushort4*)(dst + j * 4) = o;
    }
}

// ---------------------------------------------------------------------------
extern "C" void kernel_launch(void* const* d_in, const int* in_sizes, int n_in,
                              void* d_out, int out_size, void* d_ws, size_t ws_size,
                              hipStream_t stream) {
    const float* x   = (const float*)d_in[0];
    const float* Wq  = (const float*)d_in[1];
    const float* Wk  = (const float*)d_in[2];
    const float* Wv  = (const float*)d_in[3];
    const float* Wo  = (const float*)d_in[4];
    const float* qnw = (const float*)d_in[5];
    const float* knw = (const float*)d_in[6];
    const float* kc  = (const float*)d_in[7];
    const float* vc  = (const float*)d_in[8];
    const int* btab  = (const int*)d_in[9];
    const int* cseq  = (const int*)d_in[10];
    float* out = (float*)d_out;

    char* ws = (char*)d_ws;
    u16*   qb   = (u16*)(ws + 0);            // 4 MB
    u16*   kb   = (u16*)(ws + 4194304);      // 1 MB
    u16*   vb   = (u16*)(ws + 5242880);      // 1 MB
    u16*   ob   = (u16*)(ws + 6291456);      // 4 MB
    float* qf   = (float*)(ws + 10485760);   // 8 MB (dead after nrope; aliased by po)
    float* kf   = (float*)(ws + 18874368);   // 2 MB (dead after nrope; aliased by po)
    float* vf   = (float*)(ws + 20971520);   // 2 MB (dead after cvt; aliased by po)
    float* po   = (float*)(ws + 10485760);   // 32 MB partial O (1024 x 64 x 128 f32)
    float* mbuf = (float*)(ws + 44040192);   // 256 KB
    float* lbuf = (float*)(ws + 44302336);   // 256 KB

    dim3 blk(256, 1, 1);
    fgemm_bt<0><<<dim3(32, 8, 1), blk, 0, stream>>>(x, Wq, qf, 512, 4096, 4096);
    fgemm_bt<0><<<dim3(8, 8, 1),  blk, 0, stream>>>(x, Wk, kf, 512, 1024, 4096);
    fgemm_bt<0><<<dim3(8, 8, 1),  blk, 0, stream>>>(x, Wv, vf, 512, 1024, 4096);
    nrope_k<<<dim3(4096, 1, 1), blk, 0, stream>>>(qf, qb, qnw, cseq, 32, SCALE_);
    nrope_k<<<dim3(1024, 1, 1), blk, 0, stream>>>(kf, kb, knw, cseq, 8, 1.0f);
    cvt_bf16k<<<dim3(512, 1, 1), blk, 0, stream>>>(vf, vb, 131072);
    fattn_k<<<dim3(1024, 1, 1), blk, 0, stream>>>(qb, kb, vb, kc, vc, btab, cseq, po, mbuf, lbuf);
    fcomb_k<<<dim3(256, 1, 1), blk, 0, stream>>>(po, mbuf, lbuf, ob);
    fgemm_bt<1><<<dim3(32, 8, 1), blk, 0, stream>>>(ob, Wo, out, 512, 4096, 4096);
}

// Round 3
// 461.815 us; speedup vs baseline: 1.0726x; 1.0726x over previous
//
#include <hip/hip_runtime.h>

typedef unsigned short u16;
typedef float f4v __attribute__((ext_vector_type(4)));
typedef short s8v __attribute__((ext_vector_type(8)));
typedef int   i4v __attribute__((ext_vector_type(4)));

#define SCALE_ 0.08838834764831845f

__device__ __forceinline__ u16 f2b(float f) {
    union { float f; unsigned u; } c; c.f = f;
    unsigned u = c.u + 0x7fffu + ((c.u >> 16) & 1u);
    return (u16)(u >> 16);
}

typedef const __attribute__((address_space(1))) unsigned int gu32;
typedef __attribute__((address_space(3))) unsigned int lu32;
__device__ __forceinline__ void glds16(const void* g, void* l) {
    __builtin_amdgcn_global_load_lds((gu32*)g, (lu32*)l, 16, 0, 0);
}

// ---------------------------------------------------------------------------
// GEMM: C[m][n] = sum_k A[m][k] * B[n][k]   (B^T layout, both row-major)
// ---------------------------------------------------------------------------
template <int ABF16>
__global__ __launch_bounds__(256) void fgemm_bt(const void* __restrict__ Ap,
                                                const float* __restrict__ Bp,
                                                float* __restrict__ Cp,
                                                int M, int N, int K) {
    __shared__ __align__(16) char At[64 * 128];
    __shared__ __align__(16) char Bt[128 * 128];
    const int tid = threadIdx.x, lane = tid & 63, wid = tid >> 6;
    const int lm = lane & 15, lg = lane >> 4;
    const int m0 = blockIdx.y * 64, n0 = blockIdx.x * 128;
    const int NT = K >> 6;

    f4v acc[4][2];
#pragma unroll
    for (int mi = 0; mi < 4; mi++)
#pragma unroll
        for (int ni = 0; ni < 2; ni++) acc[mi][ni] = (f4v){0.f, 0.f, 0.f, 0.f};

    float fA[2][8];
    s8v   hA[2];
    float fB[4][8];

    auto loadT = [&](int kt) {
#pragma unroll
        for (int i = 0; i < 2; i++) {
            int c = tid + i * 256; int r = c >> 3, k8 = c & 7;
            if constexpr (ABF16) {
                hA[i] = *(const s8v*)((const u16*)Ap + (size_t)(m0 + r) * K + kt * 64 + k8 * 8);
            } else {
                const float* p = (const float*)Ap + (size_t)(m0 + r) * K + kt * 64 + k8 * 8;
                float4 u = *(const float4*)p, v = *(const float4*)(p + 4);
                fA[i][0] = u.x; fA[i][1] = u.y; fA[i][2] = u.z; fA[i][3] = u.w;
                fA[i][4] = v.x; fA[i][5] = v.y; fA[i][6] = v.z; fA[i][7] = v.w;
            }
        }
#pragma unroll
        for (int i = 0; i < 4; i++) {
            int c = tid + i * 256; int r = c >> 3, k8 = c & 7;
            const float* p = Bp + (size_t)(n0 + r) * K + kt * 64 + k8 * 8;
            float4 u = *(const float4*)p, v = *(const float4*)(p + 4);
            fB[i][0] = u.x; fB[i][1] = u.y; fB[i][2] = u.z; fB[i][3] = u.w;
            fB[i][4] = v.x; fB[i][5] = v.y; fB[i][6] = v.z; fB[i][7] = v.w;
        }
    };

    auto storeLDS = [&]() {
#pragma unroll
        for (int i = 0; i < 2; i++) {
            int c = tid + i * 256; int r = c >> 3, k8 = c & 7;
            s8v hv;
            if constexpr (ABF16) hv = hA[i];
            else {
#pragma unroll
                for (int j = 0; j < 8; j++) hv[j] = (short)f2b(fA[i][j]);
            }
            *(s8v*)(At + ((r * 128 + k8 * 16) ^ ((r & 7) << 4))) = hv;
        }
#pragma unroll
        for (int i = 0; i < 4; i++) {
            int c = tid + i * 256; int r = c >> 3, k8 = c & 7;
            s8v hv;
#pragma unroll
            for (int j = 0; j < 8; j++) hv[j] = (short)f2b(fB[i][j]);
            *(s8v*)(Bt + ((r * 128 + k8 * 16) ^ ((r & 7) << 4))) = hv;
        }
    };

    loadT(0);
    for (int kt = 0; kt < NT; ++kt) {
        __syncthreads();
        storeLDS();
        __syncthreads();
        if (kt + 1 < NT) loadT(kt + 1);
#pragma unroll
        for (int ks = 0; ks < 2; ks++) {
            s8v av[4], bv[2];
#pragma unroll
            for (int mi = 0; mi < 4; mi++) {
                int r = mi * 16 + lm;
                av[mi] = *(const s8v*)(At + ((r * 128 + ks * 64 + lg * 16) ^ ((r & 7) << 4)));
            }
#pragma unroll
            for (int ni = 0; ni < 2; ni++) {
                int r = wid * 32 + ni * 16 + lm;
                bv[ni] = *(const s8v*)(Bt + ((r * 128 + ks * 64 + lg * 16) ^ ((r & 7) << 4)));
            }
#pragma unroll
            for (int mi = 0; mi < 4; mi++)
#pragma unroll
                for (int ni = 0; ni < 2; ni++)
                    acc[mi][ni] = __builtin_amdgcn_mfma_f32_16x16x32_bf16(av[mi], bv[ni], acc[mi][ni], 0, 0, 0);
        }
    }

#pragma unroll
    for (int mi = 0; mi < 4; mi++)
#pragma unroll
        for (int ni = 0; ni < 2; ni++)
#pragma unroll
            for (int r = 0; r < 4; r++) {
                int m = m0 + mi * 16 + lg * 4 + r;
                int n = n0 + wid * 32 + ni * 16 + lm;
                Cp[(size_t)m * N + n] = acc[mi][ni][r];
            }
}

// ---------------------------------------------------------------------------
// Fused RMSNorm + RoPE + scale + bf16 convert.
// ---------------------------------------------------------------------------
__global__ __launch_bounds__(256) void nrope_k(const float* __restrict__ src,
                                               u16* __restrict__ dst,
                                               const float* __restrict__ w,
                                               const int* __restrict__ cseq,
                                               int nheads, float oscale) {
    const int lane = threadIdx.x & 63;
    const int rid = blockIdx.x * 4 + (threadIdx.x >> 6);
    const int s = (rid / nheads) & 127;
    const int b = rid / (nheads * 128);
    const float* p = src + (size_t)rid * 128;
    float x1 = p[lane], x2 = p[lane + 64];
    float ss = x1 * x1 + x2 * x2;
#pragma unroll
    for (int off = 1; off < 64; off <<= 1) ss += __shfl_xor(ss, off);
    float inv = rsqrtf(ss * (1.0f / 128.0f) + 1e-6f);
    float n1 = x1 * inv * w[lane];
    float n2 = x2 * inv * w[lane + 64];
    float pos = (float)(cseq[b] + s);
    float ang = pos * powf(10000.0f, -(float)lane * (1.0f / 64.0f));
    float cs = cosf(ang), sn = sinf(ang);
    dst[(size_t)rid * 128 + lane]      = f2b((n1 * cs - n2 * sn) * oscale);
    dst[(size_t)rid * 128 + lane + 64] = f2b((n2 * cs + n1 * sn) * oscale);
}

__global__ __launch_bounds__(256) void cvt_bf16k(const float* __restrict__ s,
                                                 u16* __restrict__ d, int n4) {
    int i = blockIdx.x * blockDim.x + threadIdx.x;
    if (i < n4) {
        float4 f = ((const float4*)s)[i];
        ushort4 o;
        o.x = f2b(f.x); o.y = f2b(f.y); o.z = f2b(f.z); o.w = f2b(f.w);
        ((ushort4*)d)[i] = o;
    }
}

// ---------------------------------------------------------------------------
// KV-cache -> bf16 converter, emitting MFMA-ready layouts.
// kb2[b][hk][tile66][row64][chunk16]: chunk cc stored at c16 = cc ^ (r&7).
// vb2[b][hk][tile66][pr32][chunk32]:  dword n = {V[2pr][n],V[2pr+1][n]},
//   n-chunk nc stored at c16v = nc ^ pr.
// Tiles 0..63 from fp32 paged cache (skip if t*64 >= cl); 64..65 from new
// tokens (kb/vb bf16).
// ---------------------------------------------------------------------------
__global__ __launch_bounds__(256) void cvtkv_k(const float* __restrict__ kc,
                                               const float* __restrict__ vc,
                                               const u16* __restrict__ kb,
                                               const u16* __restrict__ vb,
                                               const int* __restrict__ btab,
                                               const int* __restrict__ cseq,
                                               u16* __restrict__ kb2,
                                               u16* __restrict__ vb2) {
    const int t = blockIdx.x, hk = blockIdx.y, b = blockIdx.z;
    const int tid = threadIdx.x;
    const int cl = cseq[b];
    if (t < 64 && t * 64 >= cl) return;
    u16* kout = kb2 + ((size_t)(b * 8 + hk) * 66 + t) * 8192;
    u16* vout = vb2 + ((size_t)(b * 8 + hk) * 66 + t) * 8192;

    if (t < 64) {
#pragma unroll
        for (int i = 0; i < 4; i++) {
            int c = tid + i * 256; int r = c >> 4, c16 = c & 15;
            int cc = c16 ^ (r & 7);
            int p = t * 64 + r;
            const float* src = kc + (((size_t)btab[b * 16 + (p >> 8)] * 256 + (p & 255)) * 8 + hk) * 128 + cc * 8;
            float4 f0 = *(const float4*)src, f1 = *(const float4*)(src + 4);
            s8v v;
            v[0] = (short)f2b(f0.x); v[1] = (short)f2b(f0.y); v[2] = (short)f2b(f0.z); v[3] = (short)f2b(f0.w);
            v[4] = (short)f2b(f1.x); v[5] = (short)f2b(f1.y); v[6] = (short)f2b(f1.z); v[7] = (short)f2b(f1.w);
            *(s8v*)(kout + r * 128 + c16 * 8) = v;
        }
#pragma unroll
        for (int i = 0; i < 4; i++) {
            int c = tid + i * 256; int pr = c >> 5, c16v = c & 31;
            int nc = c16v ^ pr;
            int n = nc * 4;
            int p = t * 64 + pr * 2;
            const float* s0 = vc + (((size_t)btab[b * 16 + (p >> 8)] * 256 + (p & 255)) * 8 + hk) * 128 + n;
            float4 e = *(const float4*)s0, o = *(const float4*)(s0 + 1024);
            i4v w;
            w[0] = (int)((unsigned)f2b(e.x) | ((unsigned)f2b(o.x) << 16));
            w[1] = (int)((unsigned)f2b(e.y) | ((unsigned)f2b(o.y) << 16));
            w[2] = (int)((unsigned)f2b(e.z) | ((unsigned)f2b(o.z) << 16));
            w[3] = (int)((unsigned)f2b(e.w) | ((unsigned)f2b(o.w) << 16));
            *(i4v*)(vout + pr * 256 + c16v * 8) = w;
        }
    } else {
        int s0r = (t - 64) * 64;
#pragma unroll
        for (int i = 0; i < 4; i++) {
            int c = tid + i * 256; int r = c >> 4, c16 = c & 15;
            int cc = c16 ^ (r & 7);
            s8v v = *(const s8v*)(kb + ((size_t)(b * 128 + s0r + r) * 8 + hk) * 128 + cc * 8);
            *(s8v*)(kout + r * 128 + c16 * 8) = v;
        }
#pragma unroll
        for (int i = 0; i < 4; i++) {
            int c = tid + i * 256; int pr = c >> 5, c16v = c & 31;
            int nc = c16v ^ pr;
            int n = nc * 4;
            const u16* s0 = vb + ((size_t)(b * 128 + s0r + pr * 2) * 8 + hk) * 128 + n;
            ushort4 e = *(const ushort4*)s0, o = *(const ushort4*)(s0 + 1024);
            i4v w;
            w[0] = (int)((unsigned)e.x | ((unsigned)o.x << 16));
            w[1] = (int)((unsigned)e.y | ((unsigned)o.y << 16));
            w[2] = (int)((unsigned)e.z | ((unsigned)o.z << 16));
            w[3] = (int)((unsigned)e.w | ((unsigned)o.w << 16));
            *(i4v*)(vout + pr * 256 + c16v * 8) = w;
        }
    }
}

// ---------------------------------------------------------------------------
// Flash attention v2: bf16 pre-laid-out KV, global_load_lds staging,
// double-buffered one-tile prefetch, split-4 flash-decoding.
// ---------------------------------------------------------------------------
__global__ __launch_bounds__(256) void fattn2_k(const u16* __restrict__ qb,
                                                const u16* __restrict__ kb2,
                                                const u16* __restrict__ vb2,
                                                const int* __restrict__ cseq,
                                                float* __restrict__ po,
                                                float* __restrict__ mb,
                                                float* __restrict__ lb) {
    __shared__ __align__(16) char Ks[2][16384];
    __shared__ __align__(16) char Vs[2][16384];
    __shared__ __align__(16) char Ps[4][2048];

    const int tid = threadIdx.x, lane = tid & 63, wid = tid >> 6;
    const int lm = lane & 15, lg = lane >> 4;
    const int bid = blockIdx.x;
    const int sp = bid & 3, half = (bid >> 2) & 1, h = (bid >> 3) & 31, b = bid >> 8;
    const int hk = h >> 2;

    s8v qa[4];
    {
        const u16* qp = qb + ((size_t)((b * 128 + half * 64 + wid * 16 + lm) * 32 + h)) * 128 + lg * 8;
#pragma unroll
        for (int ks = 0; ks < 4; ks++) qa[ks] = *(const s8v*)(qp + ks * 32);
    }

    float m_run[4], l_run[4];
    f4v acc[8];
#pragma unroll
    for (int r = 0; r < 4; r++) { m_run[r] = -1e30f; l_run[r] = 0.f; }
#pragma unroll
    for (int dt = 0; dt < 8; dt++) acc[dt] = (f4v){0.f, 0.f, 0.f, 0.f};

    const int cl = cseq[b];
    const int ntc = (cl + 63) >> 6;
    const int tlo = (ntc * sp) >> 2, thi = (ntc * (sp + 1)) >> 2;
    const int ncache = thi - tlo;
    const int ntiles = ncache + (sp == 3 ? 2 : 0);

    const char* gk = (const char*)kb2 + (size_t)(b * 8 + hk) * 66 * 16384;
    const char* gv = (const char*)vb2 + (size_t)(b * 8 + hk) * 66 * 16384;

    auto STAGE = [&](int buf, int gt) {
        const char* gkt = gk + (size_t)gt * 16384 + wid * 4096 + lane * 16;
        const char* gvt = gv + (size_t)gt * 16384 + wid * 4096 + lane * 16;
        char* lk = Ks[buf] + wid * 4096;
        char* lv = Vs[buf] + wid * 4096;
#pragma unroll
        for (int i = 0; i < 4; i++) {
            glds16(gkt + i * 1024, lk + i * 1024);
            glds16(gvt + i * 1024, lv + i * 1024);
        }
    };
    auto GT = [&](int ii) { return ii < ncache ? tlo + ii : 64 + (ii - ncache); };

    if (ntiles > 0) STAGE(0, GT(0));
    asm volatile("s_waitcnt vmcnt(0)" ::: "memory");
    __syncthreads();

    for (int ii = 0; ii < ntiles; ++ii) {
        const int cur = ii & 1;
        if (ii + 1 < ntiles) STAGE(cur ^ 1, GT(ii + 1));
        const int gt = GT(ii);
        const int t0 = gt * 64;

        // ---- Q @ K^T ----
        f4v sc[4];
#pragma unroll
        for (int ct = 0; ct < 4; ct++) sc[ct] = (f4v){0.f, 0.f, 0.f, 0.f};
#pragma unroll
        for (int ct = 0; ct < 4; ct++) {
#pragma unroll
            for (int ks = 0; ks < 4; ks++) {
                int r = ct * 16 + lm;
                s8v kf = *(const s8v*)(Ks[cur] + ((r * 256 + ks * 64 + lg * 16) ^ ((r & 7) << 4)));
                sc[ct] = __builtin_amdgcn_mfma_f32_16x16x32_bf16(qa[ks], kf, sc[ct], 0, 0, 0);
            }
        }
        if (gt < 64 && (t0 + 64 > cl)) {
#pragma unroll
            for (int ct = 0; ct < 4; ct++) {
                int p = t0 + ct * 16 + lm;
                if (p >= cl) { sc[ct][0] = -1e30f; sc[ct][1] = -1e30f; sc[ct][2] = -1e30f; sc[ct][3] = -1e30f; }
            }
        }

        // ---- online softmax ----
        float mnew[4], corr[4], rsum[4];
#pragma unroll
        for (int r = 0; r < 4; r++) {
            float mt = fmaxf(fmaxf(sc[0][r], sc[1][r]), fmaxf(sc[2][r], sc[3][r]));
#pragma unroll
            for (int off = 1; off < 16; off <<= 1) mt = fmaxf(mt, __shfl_xor(mt, off));
            float mn = fmaxf(m_run[r], mt);
            corr[r] = __expf(m_run[r] - mn);
            m_run[r] = mn;
            mnew[r] = mn;
            rsum[r] = 0.f;
        }
#pragma unroll
        for (int ct = 0; ct < 4; ct++) {
#pragma unroll
            for (int r = 0; r < 4; r++) {
                float pv = __expf(sc[ct][r] - mnew[r]);
                rsum[r] += pv;
                int row = lg * 4 + r;
                *(u16*)(Ps[wid] + ((row * 128 + (ct * 16 + lm) * 2) ^ ((row & 7) << 4))) = f2b(pv);
            }
        }
#pragma unroll
        for (int r = 0; r < 4; r++) {
            float rs = rsum[r];
#pragma unroll
            for (int off = 1; off < 16; off <<= 1) rs += __shfl_xor(rs, off);
            l_run[r] = l_run[r] * corr[r] + rs;
        }
#pragma unroll
        for (int dt = 0; dt < 8; dt++) {
#pragma unroll
            for (int r = 0; r < 4; r++) acc[dt][r] *= corr[r];
        }

        // ---- P A-frags ----
        s8v pa[2];
#pragma unroll
        for (int k2 = 0; k2 < 2; k2++)
            pa[k2] = *(const s8v*)(Ps[wid] + ((lm * 128 + k2 * 64 + lg * 16) ^ ((lm & 7) << 4)));

        // ---- P @ V ----
#pragma unroll
        for (int k2 = 0; k2 < 2; k2++) {
#pragma unroll
            for (int dt = 0; dt < 8; dt++) {
                i4v vv;
#pragma unroll
                for (int t = 0; t < 4; t++) {
                    int p = k2 * 16 + lg * 4 + t;
                    vv[t] = *(const int*)(Vs[cur] + p * 512 + ((((dt * 16 + lm) * 4)) ^ ((p & 31) << 4)));
                }
                union { i4v i; s8v s; } u; u.i = vv;
                acc[dt] = __builtin_amdgcn_mfma_f32_16x16x32_bf16(pa[k2], u.s, acc[dt], 0, 0, 0);
            }
        }

        asm volatile("s_waitcnt vmcnt(0)" ::: "memory");
        __syncthreads();
    }

#pragma unroll
    for (int dt = 0; dt < 8; dt++) {
#pragma unroll
        for (int r = 0; r < 4; r++) {
            int row = wid * 16 + lg * 4 + r;
            po[((size_t)bid * 64 + row) * 128 + dt * 16 + lm] = acc[dt][r];
        }
    }
    if (lm == 0) {
#pragma unroll
        for (int r = 0; r < 4; r++) {
            int row = wid * 16 + lg * 4 + r;
            mb[(size_t)bid * 64 + row] = m_run[r];
            lb[(size_t)bid * 64 + row] = l_run[r];
        }
    }
}

// ---------------------------------------------------------------------------
// Flash attention (fallback, round-2 version, fp32 KV reg-staged).
// ---------------------------------------------------------------------------
__global__ __launch_bounds__(256) void fattn_k(const u16* __restrict__ qb,
                                               const u16* __restrict__ kb,
                                               const u16* __restrict__ vb,
                                               const float* __restrict__ kc,
                                               const float* __restrict__ vc,
                                               const int* __restrict__ btab,
                                               const int* __restrict__ cseq,
                                               float* __restrict__ po,
                                               float* __restrict__ mb,
                                               float* __restrict__ lb) {
    __shared__ __align__(16) char Ks[64 * 256];
    __shared__ __align__(16) char Vs[32 * 512];
    __shared__ __align__(16) char Ps[4][2048];

    const int tid = threadIdx.x, lane = tid & 63, wid = tid >> 6;
    const int lm = lane & 15, lg = lane >> 4;
    const int bid = blockIdx.x;
    const int sp = bid & 3, half = (bid >> 2) & 1, h = (bid >> 3) & 31, b = bid >> 8;
    const int hk = h >> 2;

    s8v qa[4];
    {
        const u16* qp = qb + ((size_t)((b * 128 + half * 64 + wid * 16 + lm) * 32 + h)) * 128 + lg * 8;
#pragma unroll
        for (int ks = 0; ks < 4; ks++) qa[ks] = *(const s8v*)(qp + ks * 32);
    }

    float m_run[4], l_run[4];
    f4v acc[8];
#pragma unroll
    for (int r = 0; r < 4; r++) { m_run[r] = -1e30f; l_run[r] = 0.f; }
#pragma unroll
    for (int dt = 0; dt < 8; dt++) acc[dt] = (f4v){0.f, 0.f, 0.f, 0.f};

    const int cl = cseq[b];
    const int ntc = (cl + 63) >> 6;
    const int tlo = (ntc * sp) >> 2, thi = (ntc * (sp + 1)) >> 2;
    const int ncache = thi - tlo;
    const int ntiles = ncache + (sp == 3 ? 2 : 0);

    for (int ii = 0; ii < ntiles; ++ii) {
        const bool isnew = ii >= ncache;
        const int t0 = isnew ? (4096 + (ii - ncache) * 64) : (tlo + ii) * 64;
        __syncthreads();

        if (!isnew) {
            f4v kr[4][2];
#pragma unroll
            for (int i = 0; i < 4; i++) {
                int c = tid + i * 256; int r = c >> 4, d8 = c & 15;
                int p = t0 + r;
                const float* src = kc + (((size_t)btab[b * 16 + (p >> 8)] * 256 + (p & 255)) * 8 + hk) * 128 + d8 * 8;
                kr[i][0] = *(const f4v*)src; kr[i][1] = *(const f4v*)(src + 4);
            }
            f4v vr[2][4];
#pragma unroll
            for (int i = 0; i < 2; i++) {
                int c = tid + i * 256; int pr = c >> 4, d8 = c & 15, n0 = d8 * 8;
                int prow = t0 + pr * 2;
                const float* src = vc + (((size_t)btab[b * 16 + (prow >> 8)] * 256 + (prow & 255)) * 8 + hk) * 128 + n0;
                vr[i][0] = *(const f4v*)src;          vr[i][1] = *(const f4v*)(src + 4);
                vr[i][2] = *(const f4v*)(src + 1024); vr[i][3] = *(const f4v*)(src + 1028);
            }
#pragma unroll
            for (int i = 0; i < 4; i++) {
                int c = tid + i * 256; int r = c >> 4, d8 = c & 15;
                s8v v;
#pragma unroll
                for (int j = 0; j < 4; j++) { v[j] = (short)f2b(kr[i][0][j]); v[j + 4] = (short)f2b(kr[i][1][j]); }
                *(s8v*)(Ks + ((r * 256 + d8 * 16) ^ ((r & 7) << 4))) = v;
            }
#pragma unroll
            for (int i = 0; i < 2; i++) {
                int c = tid + i * 256; int pr = c >> 4, d8 = c & 15, n0 = d8 * 8;
                i4v w1, w2;
#pragma unroll
                for (int j = 0; j < 4; j++) {
                    w1[j] = (int)((unsigned)f2b(vr[i][0][j]) | ((unsigned)f2b(vr[i][2][j]) << 16));
                    w2[j] = (int)((unsigned)f2b(vr[i][1][j]) | ((unsigned)f2b(vr[i][3][j]) << 16));
                }
                int swz = (pr & 31) << 4;
                *(i4v*)(Vs + pr * 512 + ((n0 * 4) ^ swz))      = w1;
                *(i4v*)(Vs + pr * 512 + ((n0 * 4 + 16) ^ swz)) = w2;
            }
        } else {
            int s0 = t0 - 4096;
            s8v kr2[4];
#pragma unroll
            for (int i = 0; i < 4; i++) {
                int c = tid + i * 256; int r = c >> 4, d8 = c & 15;
                kr2[i] = *(const s8v*)(kb + ((size_t)(b * 128 + s0 + r) * 8 + hk) * 128 + d8 * 8);
            }
            s8v vre[2], vro[2];
#pragma unroll
            for (int i = 0; i < 2; i++) {
                int c = tid + i * 256; int pr = c >> 4, d8 = c & 15, n0 = d8 * 8;
                const u16* src = vb + ((size_t)(b * 128 + s0 + pr * 2) * 8 + hk) * 128 + n0;
                vre[i] = *(const s8v*)src;
                vro[i] = *(const s8v*)(src + 1024);
            }
#pragma unroll
            for (int i = 0; i < 4; i++) {
                int c = tid + i * 256; int r = c >> 4, d8 = c & 15;
                *(s8v*)(Ks + ((r * 256 + d8 * 16) ^ ((r & 7) << 4))) = kr2[i];
            }
#pragma unroll
            for (int i = 0; i < 2; i++) {
                int c = tid + i * 256; int pr = c >> 4, d8 = c & 15, n0 = d8 * 8;
                i4v w1, w2;
#pragma unroll
                for (int j = 0; j < 4; j++) {
                    w1[j] = (int)((unsigned)(u16)vre[i][j] | ((unsigned)(u16)vro[i][j] << 16));
                    w2[j] = (int)((unsigned)(u16)vre[i][j + 4] | ((unsigned)(u16)vro[i][j + 4] << 16));
                }
                int swz = (pr & 31) << 4;
                *(i4v*)(Vs + pr * 512 + ((n0 * 4) ^ swz))      = w1;
                *(i4v*)(Vs + pr * 512 + ((n0 * 4 + 16) ^ swz)) = w2;
            }
        }
        __syncthreads();

        f4v sc[4];
#pragma unroll
        for (int ct = 0; ct < 4; ct++) sc[ct] = (f4v){0.f, 0.f, 0.f, 0.f};
#pragma unroll
        for (int ct = 0; ct < 4; ct++) {
#pragma unroll
            for (int ks = 0; ks < 4; ks++) {
                int r = ct * 16 + lm;
                s8v kf = *(const s8v*)(Ks + ((r * 256 + ks * 64 + lg * 16) ^ ((r & 7) << 4)));
                sc[ct] = __builtin_amdgcn_mfma_f32_16x16x32_bf16(qa[ks], kf, sc[ct], 0, 0, 0);
            }
        }
        if (!isnew && (t0 + 64 > cl)) {
#pragma unroll
            for (int ct = 0; ct < 4; ct++) {
                int p = t0 + ct * 16 + lm;
                if (p >= cl) { sc[ct][0] = -1e30f; sc[ct][1] = -1e30f; sc[ct][2] = -1e30f; sc[ct][3] = -1e30f; }
            }
        }

        float mnew[4], corr[4], rsum[4];
#pragma unroll
        for (int r = 0; r < 4; r++) {
            float mt = fmaxf(fmaxf(sc[0][r], sc[1][r]), fmaxf(sc[2][r], sc[3][r]));
#pragma unroll
            for (int off = 1; off < 16; off <<= 1) mt = fmaxf(mt, __shfl_xor(mt, off));
            float mn = fmaxf(m_run[r], mt);
            corr[r] = __expf(m_run[r] - mn);
            m_run[r] = mn;
            mnew[r] = mn;
            rsum[r] = 0.f;
        }
#pragma unroll
        for (int ct = 0; ct < 4; ct++) {
#pragma unroll
            for (int r = 0; r < 4; r++) {
                float pv = __expf(sc[ct][r] - mnew[r]);
                rsum[r] += pv;
                int row = lg * 4 + r;
                *(u16*)(Ps[wid] + ((row * 128 + (ct * 16 + lm) * 2) ^ ((row & 7) << 4))) = f2b(pv);
            }
        }
#pragma unroll
        for (int r = 0; r < 4; r++) {
            float rs = rsum[r];
#pragma unroll
            for (int off = 1; off < 16; off <<= 1) rs += __shfl_xor(rs, off);
            l_run[r] = l_run[r] * corr[r] + rs;
        }
#pragma unroll
        for (int dt = 0; dt < 8; dt++) {
#pragma unroll
            for (int r = 0; r < 4; r++) acc[dt][r] *= corr[r];
        }

        s8v pa[2];
#pragma unroll
        for (int k2 = 0; k2 < 2; k2++)
            pa[k2] = *(const s8v*)(Ps[wid] + ((lm * 128 + k2 * 64 + lg * 16) ^ ((lm & 7) << 4)));

#pragma unroll
        for (int k2 = 0; k2 < 2; k2++) {
#pragma unroll
            for (int dt = 0; dt < 8; dt++) {
                i4v vv;
#pragma unroll
                for (int t = 0; t < 4; t++) {
                    int p = k2 * 16 + lg * 4 + t;
                    vv[t] = *(const int*)(Vs + p * 512 + ((((dt * 16 + lm) * 4)) ^ ((p & 31) << 4)));
                }
                union { i4v i; s8v s; } u; u.i = vv;
                acc[dt] = __builtin_amdgcn_mfma_f32_16x16x32_bf16(pa[k2], u.s, acc[dt], 0, 0, 0);
            }
        }
    }

#pragma unroll
    for (int dt = 0; dt < 8; dt++) {
#pragma unroll
        for (int r = 0; r < 4; r++) {
            int row = wid * 16 + lg * 4 + r;
            po[((size_t)bid * 64 + row) * 128 + dt * 16 + lm] = acc[dt][r];
        }
    }
    if (lm == 0) {
#pragma unroll
        for (int r = 0; r < 4; r++) {
            int row = wid * 16 + lg * 4 + r;
            mb[(size_t)bid * 64 + row] = m_run[r];
            lb[(size_t)bid * 64 + row] = l_run[r];
        }
    }
}

// ---------------------------------------------------------------------------
// Combine 4 splits.
// ---------------------------------------------------------------------------
__global__ __launch_bounds__(256) void fcomb_k(const float* __restrict__ po,
                                               const float* __restrict__ mb,
                                               const float* __restrict__ lb,
                                               u16* __restrict__ ob) {
    const int pid = blockIdx.x, t = threadIdx.x;
    const int row = t >> 2, dq = t & 3;
    const int half = pid & 1, h = (pid >> 1) & 31, b = pid >> 6;
    float m[4], l[4];
#pragma unroll
    for (int i = 0; i < 4; i++) {
        m[i] = mb[(size_t)(pid * 4 + i) * 64 + row];
        l[i] = lb[(size_t)(pid * 4 + i) * 64 + row];
    }
    float M = fmaxf(fmaxf(m[0], m[1]), fmaxf(m[2], m[3]));
    float w[4], L = 0.f;
#pragma unroll
    for (int i = 0; i < 4; i++) { w[i] = __expf(m[i] - M); L += w[i] * l[i]; }
    float invL = 1.0f / L;
    u16* dst = ob + ((size_t)(b * 128 + half * 64 + row) * 32 + h) * 128 + dq * 32;
#pragma unroll
    for (int j = 0; j < 8; j++) {
        f4v s = (f4v){0.f, 0.f, 0.f, 0.f};
#pragma unroll
        for (int i = 0; i < 4; i++) {
            f4v a = *(const f4v*)(po + ((size_t)(pid * 4 + i) * 64 + row) * 128 + dq * 32 + j * 4);
            s += w[i] * a;
        }
        ushort4 o;
        o.x = f2b(s[0] * invL); o.y = f2b(s[1] * invL);
        o.z = f2b(s[2] * invL); o.w = f2b(s[3] * invL);
        *(ushort4*)(dst + j * 4) = o;
    }
}

// ---------------------------------------------------------------------------
extern "C" void kernel_launch(void* const* d_in, const int* in_sizes, int n_in,
                              void* d_out, int out_size, void* d_ws, size_t ws_size,
                              hipStream_t stream) {
    const float* x   = (const float*)d_in[0];
    const float* Wq  = (const float*)d_in[1];
    const float* Wk  = (const float*)d_in[2];
    const float* Wv  = (const float*)d_in[3];
    const float* Wo  = (const float*)d_in[4];
    const float* qnw = (const float*)d_in[5];
    const float* knw = (const float*)d_in[6];
    const float* kc  = (const float*)d_in[7];
    const float* vc  = (const float*)d_in[8];
    const int* btab  = (const int*)d_in[9];
    const int* cseq  = (const int*)d_in[10];
    float* out = (float*)d_out;

    char* ws = (char*)d_ws;
    dim3 blk(256, 1, 1);
    const bool fast = ws_size >= 113770496ull;

    if (fast) {
        u16*   qb   = (u16*)(ws + 0);
        u16*   kb   = (u16*)(ws + 4194304);
        u16*   vb   = (u16*)(ws + 5242880);
        u16*   ob   = (u16*)(ws + 6291456);
        float* mbuf = (float*)(ws + 10485760);
        float* lbuf = (float*)(ws + 10747904);
        float* po   = (float*)(ws + 11010048);   // 32 MB
        float* qf   = (float*)(ws + 11010048);   // alias (dead before fattn2)
        float* kf   = (float*)(ws + 19398656);
        float* vf   = (float*)(ws + 21495808);
        u16*   kb2  = (u16*)(ws + 44564480);     // 33 MB
        u16*   vb2  = (u16*)(ws + 79167488);     // 33 MB

        fgemm_bt<0><<<dim3(32, 8, 1), blk, 0, stream>>>(x, Wq, qf, 512, 4096, 4096);
        fgemm_bt<0><<<dim3(8, 8, 1),  blk, 0, stream>>>(x, Wk, kf, 512, 1024, 4096);
        fgemm_bt<0><<<dim3(8, 8, 1),  blk, 0, stream>>>(x, Wv, vf, 512, 1024, 4096);
        nrope_k<<<dim3(4096, 1, 1), blk, 0, stream>>>(qf, qb, qnw, cseq, 32, SCALE_);
        nrope_k<<<dim3(1024, 1, 1), blk, 0, stream>>>(kf, kb, knw, cseq, 8, 1.0f);
        cvt_bf16k<<<dim3(512, 1, 1), blk, 0, stream>>>(vf, vb, 131072);
        cvtkv_k<<<dim3(66, 8, 4), blk, 0, stream>>>(kc, vc, kb, vb, btab, cseq, kb2, vb2);
        fattn2_k<<<dim3(1024, 1, 1), blk, 0, stream>>>(qb, kb2, vb2, cseq, po, mbuf, lbuf);
        fcomb_k<<<dim3(256, 1, 1), blk, 0, stream>>>(po, mbuf, lbuf, ob);
        fgemm_bt<1><<<dim3(32, 8, 1), blk, 0, stream>>>(ob, Wo, out, 512, 4096, 4096);
    } else {
        u16*   qb   = (u16*)(ws + 0);
        u16*   kb   = (u16*)(ws + 4194304);
        u16*   vb   = (u16*)(ws + 5242880);
        u16*   ob   = (u16*)(ws + 6291456);
        float* qf   = (float*)(ws + 10485760);
        float* kf   = (float*)(ws + 18874368);
        float* vf   = (float*)(ws + 20971520);
        float* po   = (float*)(ws + 10485760);
        float* mbuf = (float*)(ws + 44040192);
        float* lbuf = (float*)(ws + 44302336);

        fgemm_bt<0><<<dim3(32, 8, 1), blk, 0, stream>>>(x, Wq, qf, 512, 4096, 4096);
        fgemm_bt<0><<<dim3(8, 8, 1),  blk, 0, stream>>>(x, Wk, kf, 512, 1024, 4096);
        fgemm_bt<0><<<dim3(8, 8, 1),  blk, 0, stream>>>(x, Wv, vf, 512, 1024, 4096);
        nrope_k<<<dim3(4096, 1, 1), blk, 0, stream>>>(qf, qb, qnw, cseq, 32, SCALE_);
        nrope_k<<<dim3(1024, 1, 1), blk, 0, stream>>>(kf, kb, knw, cseq, 8, 1.0f);
        cvt_bf16k<<<dim3(512, 1, 1), blk, 0, stream>>>(vf, vb, 131072);
        fattn_k<<<dim3(1024, 1, 1), blk, 0, stream>>>(qb, kb, vb, kc, vc, btab, cseq, po, mbuf, lbuf);
        fcomb_k<<<dim3(256, 1, 1), blk, 0, stream>>>(po, mbuf, lbuf, ob);
        fgemm_bt<1><<<dim3(32, 8, 1), blk, 0, stream>>>(ob, Wo, out, 512, 4096, 4096);
    }
}

// Round 4
// 265.518 us; speedup vs baseline: 1.8655x; 1.7393x over previous
//
#include <hip/hip_runtime.h>

typedef unsigned short u16;
typedef float f4v __attribute__((ext_vector_type(4)));
typedef short s8v __attribute__((ext_vector_type(8)));
typedef int   i4v __attribute__((ext_vector_type(4)));

#define SCALE_ 0.08838834764831845f

__device__ __forceinline__ u16 f2b(float f) {
    union { float f; unsigned u; } c; c.f = f;
    unsigned u = c.u + 0x7fffu + ((c.u >> 16) & 1u);
    return (u16)(u >> 16);
}

typedef const __attribute__((address_space(1))) unsigned int gu32;
typedef __attribute__((address_space(3))) unsigned int lu32;
__device__ __forceinline__ void glds16(const void* g, void* l) {
    __builtin_amdgcn_global_load_lds((gu32*)g, (lu32*)l, 16, 0, 0);
}

// ---------------------------------------------------------------------------
// Split-K GEMM: C[z][m][n] = sum_{k in slice z} A[m][k] * B[n][k]
// Tile 64x128, BK=64, 4 waves, reg-prefetch next K-tile. blockIdx.z = K-slice.
// ---------------------------------------------------------------------------
template <int ABF16>
__global__ __launch_bounds__(256) void fgemm_sk(const void* __restrict__ Ap,
                                                const float* __restrict__ Bp,
                                                float* __restrict__ Cp,
                                                int M, int N, int K, int Ksl) {
    __shared__ __align__(16) char At[64 * 128];
    __shared__ __align__(16) char Bt[128 * 128];
    const int tid = threadIdx.x, lane = tid & 63, wid = tid >> 6;
    const int lm = lane & 15, lg = lane >> 4;
    const int m0 = blockIdx.y * 64, n0 = blockIdx.x * 128;
    const int k0 = blockIdx.z * Ksl;
    const int NT = Ksl >> 6;
    Cp += (size_t)blockIdx.z * M * N;

    f4v acc[4][2];
#pragma unroll
    for (int mi = 0; mi < 4; mi++)
#pragma unroll
        for (int ni = 0; ni < 2; ni++) acc[mi][ni] = (f4v){0.f, 0.f, 0.f, 0.f};

    float fA[2][8];
    s8v   hA[2];
    float fB[4][8];

    auto loadT = [&](int kt) {
#pragma unroll
        for (int i = 0; i < 2; i++) {
            int c = tid + i * 256; int r = c >> 3, k8 = c & 7;
            if constexpr (ABF16) {
                hA[i] = *(const s8v*)((const u16*)Ap + (size_t)(m0 + r) * K + k0 + kt * 64 + k8 * 8);
            } else {
                const float* p = (const float*)Ap + (size_t)(m0 + r) * K + k0 + kt * 64 + k8 * 8;
                float4 u = *(const float4*)p, v = *(const float4*)(p + 4);
                fA[i][0] = u.x; fA[i][1] = u.y; fA[i][2] = u.z; fA[i][3] = u.w;
                fA[i][4] = v.x; fA[i][5] = v.y; fA[i][6] = v.z; fA[i][7] = v.w;
            }
        }
#pragma unroll
        for (int i = 0; i < 4; i++) {
            int c = tid + i * 256; int r = c >> 3, k8 = c & 7;
            const float* p = Bp + (size_t)(n0 + r) * K + k0 + kt * 64 + k8 * 8;
            float4 u = *(const float4*)p, v = *(const float4*)(p + 4);
            fB[i][0] = u.x; fB[i][1] = u.y; fB[i][2] = u.z; fB[i][3] = u.w;
            fB[i][4] = v.x; fB[i][5] = v.y; fB[i][6] = v.z; fB[i][7] = v.w;
        }
    };

    auto storeLDS = [&]() {
#pragma unroll
        for (int i = 0; i < 2; i++) {
            int c = tid + i * 256; int r = c >> 3, k8 = c & 7;
            s8v hv;
            if constexpr (ABF16) hv = hA[i];
            else {
#pragma unroll
                for (int j = 0; j < 8; j++) hv[j] = (short)f2b(fA[i][j]);
            }
            *(s8v*)(At + ((r * 128 + k8 * 16) ^ ((r & 7) << 4))) = hv;
        }
#pragma unroll
        for (int i = 0; i < 4; i++) {
            int c = tid + i * 256; int r = c >> 3, k8 = c & 7;
            s8v hv;
#pragma unroll
            for (int j = 0; j < 8; j++) hv[j] = (short)f2b(fB[i][j]);
            *(s8v*)(Bt + ((r * 128 + k8 * 16) ^ ((r & 7) << 4))) = hv;
        }
    };

    loadT(0);
    for (int kt = 0; kt < NT; ++kt) {
        __syncthreads();
        storeLDS();
        __syncthreads();
        if (kt + 1 < NT) loadT(kt + 1);
#pragma unroll
        for (int ks = 0; ks < 2; ks++) {
            s8v av[4], bv[2];
#pragma unroll
            for (int mi = 0; mi < 4; mi++) {
                int r = mi * 16 + lm;
                av[mi] = *(const s8v*)(At + ((r * 128 + ks * 64 + lg * 16) ^ ((r & 7) << 4)));
            }
#pragma unroll
            for (int ni = 0; ni < 2; ni++) {
                int r = wid * 32 + ni * 16 + lm;
                bv[ni] = *(const s8v*)(Bt + ((r * 128 + ks * 64 + lg * 16) ^ ((r & 7) << 4)));
            }
#pragma unroll
            for (int mi = 0; mi < 4; mi++)
#pragma unroll
                for (int ni = 0; ni < 2; ni++)
                    acc[mi][ni] = __builtin_amdgcn_mfma_f32_16x16x32_bf16(av[mi], bv[ni], acc[mi][ni], 0, 0, 0);
        }
    }

#pragma unroll
    for (int mi = 0; mi < 4; mi++)
#pragma unroll
        for (int ni = 0; ni < 2; ni++)
#pragma unroll
            for (int r = 0; r < 4; r++) {
                int m = m0 + mi * 16 + lg * 4 + r;
                int n = n0 + wid * 32 + ni * 16 + lm;
                Cp[(size_t)m * N + n] = acc[mi][ni][r];
            }
}

// ---------------------------------------------------------------------------
// Fused K-slice reduce + RMSNorm + RoPE + scale + bf16 convert.
// ---------------------------------------------------------------------------
__global__ __launch_bounds__(256) void nrope_k(const float* __restrict__ src,
                                               u16* __restrict__ dst,
                                               const float* __restrict__ w,
                                               const int* __restrict__ cseq,
                                               int nheads, float oscale,
                                               int nsl, size_t sls) {
    const int lane = threadIdx.x & 63;
    const int rid = blockIdx.x * 4 + (threadIdx.x >> 6);
    const int s = (rid / nheads) & 127;
    const int b = rid / (nheads * 128);
    const float* p = src + (size_t)rid * 128;
    float x1 = 0.f, x2 = 0.f;
    for (int sl = 0; sl < nsl; sl++) {
        x1 += p[sl * sls + lane];
        x2 += p[sl * sls + lane + 64];
    }
    float ss = x1 * x1 + x2 * x2;
#pragma unroll
    for (int off = 1; off < 64; off <<= 1) ss += __shfl_xor(ss, off);
    float inv = rsqrtf(ss * (1.0f / 128.0f) + 1e-6f);
    float n1 = x1 * inv * w[lane];
    float n2 = x2 * inv * w[lane + 64];
    float pos = (float)(cseq[b] + s);
    float ang = pos * powf(10000.0f, -(float)lane * (1.0f / 64.0f));
    float cs = cosf(ang), sn = sinf(ang);
    dst[(size_t)rid * 128 + lane]      = f2b((n1 * cs - n2 * sn) * oscale);
    dst[(size_t)rid * 128 + lane + 64] = f2b((n2 * cs + n1 * sn) * oscale);
}

// K-slice reduce + bf16 convert.
__global__ __launch_bounds__(256) void cvt_bf16k(const float* __restrict__ s,
                                                 u16* __restrict__ d, int n4,
                                                 int nsl, size_t sls) {
    int i = blockIdx.x * blockDim.x + threadIdx.x;
    if (i < n4) {
        f4v f = (f4v){0.f, 0.f, 0.f, 0.f};
        for (int sl = 0; sl < nsl; sl++)
            f += *(const f4v*)(s + sl * sls + (size_t)i * 4);
        ushort4 o;
        o.x = f2b(f[0]); o.y = f2b(f[1]); o.z = f2b(f[2]); o.w = f2b(f[3]);
        ((ushort4*)d)[i] = o;
    }
}

// Sum 4 K-slices -> fp32 out.
__global__ __launch_bounds__(256) void red4_k(const float* __restrict__ p,
                                              float* __restrict__ out, int n4,
                                              size_t sls) {
    int i = blockIdx.x * blockDim.x + threadIdx.x;
    if (i < n4) {
        f4v s = (f4v){0.f, 0.f, 0.f, 0.f};
#pragma unroll
        for (int sl = 0; sl < 4; sl++)
            s += *(const f4v*)(p + sl * sls + (size_t)i * 4);
        *(f4v*)(out + (size_t)i * 4) = s;
    }
}

// ---------------------------------------------------------------------------
// KV-cache -> bf16 converter, emitting MFMA-ready swizzled layouts.
// ---------------------------------------------------------------------------
__global__ __launch_bounds__(256) void cvtkv_k(const float* __restrict__ kc,
                                               const float* __restrict__ vc,
                                               const u16* __restrict__ kb,
                                               const u16* __restrict__ vb,
                                               const int* __restrict__ btab,
                                               const int* __restrict__ cseq,
                                               u16* __restrict__ kb2,
                                               u16* __restrict__ vb2) {
    const int t = blockIdx.x, hk = blockIdx.y, b = blockIdx.z;
    const int tid = threadIdx.x;
    const int cl = cseq[b];
    if (t < 64 && t * 64 >= cl) return;
    u16* kout = kb2 + ((size_t)(b * 8 + hk) * 66 + t) * 8192;
    u16* vout = vb2 + ((size_t)(b * 8 + hk) * 66 + t) * 8192;

    if (t < 64) {
#pragma unroll
        for (int i = 0; i < 4; i++) {
            int c = tid + i * 256; int r = c >> 4, c16 = c & 15;
            int cc = c16 ^ (r & 7);
            int p = t * 64 + r;
            const float* src = kc + (((size_t)btab[b * 16 + (p >> 8)] * 256 + (p & 255)) * 8 + hk) * 128 + cc * 8;
            float4 f0 = *(const float4*)src, f1 = *(const float4*)(src + 4);
            s8v v;
            v[0] = (short)f2b(f0.x); v[1] = (short)f2b(f0.y); v[2] = (short)f2b(f0.z); v[3] = (short)f2b(f0.w);
            v[4] = (short)f2b(f1.x); v[5] = (short)f2b(f1.y); v[6] = (short)f2b(f1.z); v[7] = (short)f2b(f1.w);
            *(s8v*)(kout + r * 128 + c16 * 8) = v;
        }
#pragma unroll
        for (int i = 0; i < 4; i++) {
            int c = tid + i * 256; int pr = c >> 5, c16v = c & 31;
            int nc = c16v ^ pr;
            int n = nc * 4;
            int p = t * 64 + pr * 2;
            const float* s0 = vc + (((size_t)btab[b * 16 + (p >> 8)] * 256 + (p & 255)) * 8 + hk) * 128 + n;
            float4 e = *(const float4*)s0, o = *(const float4*)(s0 + 1024);
            i4v w;
            w[0] = (int)((unsigned)f2b(e.x) | ((unsigned)f2b(o.x) << 16));
            w[1] = (int)((unsigned)f2b(e.y) | ((unsigned)f2b(o.y) << 16));
            w[2] = (int)((unsigned)f2b(e.z) | ((unsigned)f2b(o.z) << 16));
            w[3] = (int)((unsigned)f2b(e.w) | ((unsigned)f2b(o.w) << 16));
            *(i4v*)(vout + pr * 256 + c16v * 8) = w;
        }
    } else {
        int s0r = (t - 64) * 64;
#pragma unroll
        for (int i = 0; i < 4; i++) {
            int c = tid + i * 256; int r = c >> 4, c16 = c & 15;
            int cc = c16 ^ (r & 7);
            s8v v = *(const s8v*)(kb + ((size_t)(b * 128 + s0r + r) * 8 + hk) * 128 + cc * 8);
            *(s8v*)(kout + r * 128 + c16 * 8) = v;
        }
#pragma unroll
        for (int i = 0; i < 4; i++) {
            int c = tid + i * 256; int pr = c >> 5, c16v = c & 31;
            int nc = c16v ^ pr;
            int n = nc * 4;
            const u16* s0 = vb + ((size_t)(b * 128 + s0r + pr * 2) * 8 + hk) * 128 + n;
            ushort4 e = *(const ushort4*)s0, o = *(const ushort4*)(s0 + 1024);
            i4v w;
            w[0] = (int)((unsigned)e.x | ((unsigned)o.x << 16));
            w[1] = (int)((unsigned)e.y | ((unsigned)o.y << 16));
            w[2] = (int)((unsigned)e.z | ((unsigned)o.z << 16));
            w[3] = (int)((unsigned)e.w | ((unsigned)o.w << 16));
            *(i4v*)(vout + pr * 256 + c16v * 8) = w;
        }
    }
}

// ---------------------------------------------------------------------------
// Flash attention v2: bf16 pre-laid-out KV, global_load_lds staging,
// double-buffered one-tile prefetch, split-4 flash-decoding.
// ---------------------------------------------------------------------------
__global__ __launch_bounds__(256) void fattn2_k(const u16* __restrict__ qb,
                                                const u16* __restrict__ kb2,
                                                const u16* __restrict__ vb2,
                                                const int* __restrict__ cseq,
                                                float* __restrict__ po,
                                                float* __restrict__ mb,
                                                float* __restrict__ lb) {
    __shared__ __align__(16) char Ks[2][16384];
    __shared__ __align__(16) char Vs[2][16384];
    __shared__ __align__(16) char Ps[4][2048];

    const int tid = threadIdx.x, lane = tid & 63, wid = tid >> 6;
    const int lm = lane & 15, lg = lane >> 4;
    const int bid = blockIdx.x;
    const int sp = bid & 3, half = (bid >> 2) & 1, h = (bid >> 3) & 31, b = bid >> 8;
    const int hk = h >> 2;

    s8v qa[4];
    {
        const u16* qp = qb + ((size_t)((b * 128 + half * 64 + wid * 16 + lm) * 32 + h)) * 128 + lg * 8;
#pragma unroll
        for (int ks = 0; ks < 4; ks++) qa[ks] = *(const s8v*)(qp + ks * 32);
    }

    float m_run[4], l_run[4];
    f4v acc[8];
#pragma unroll
    for (int r = 0; r < 4; r++) { m_run[r] = -1e30f; l_run[r] = 0.f; }
#pragma unroll
    for (int dt = 0; dt < 8; dt++) acc[dt] = (f4v){0.f, 0.f, 0.f, 0.f};

    const int cl = cseq[b];
    const int ntc = (cl + 63) >> 6;
    const int tlo = (ntc * sp) >> 2, thi = (ntc * (sp + 1)) >> 2;
    const int ncache = thi - tlo;
    const int ntiles = ncache + (sp == 3 ? 2 : 0);

    const char* gk = (const char*)kb2 + (size_t)(b * 8 + hk) * 66 * 16384;
    const char* gv = (const char*)vb2 + (size_t)(b * 8 + hk) * 66 * 16384;

    auto STAGE = [&](int buf, int gt) {
        const char* gkt = gk + (size_t)gt * 16384 + wid * 4096 + lane * 16;
        const char* gvt = gv + (size_t)gt * 16384 + wid * 4096 + lane * 16;
        char* lk = Ks[buf] + wid * 4096;
        char* lv = Vs[buf] + wid * 4096;
#pragma unroll
        for (int i = 0; i < 4; i++) {
            glds16(gkt + i * 1024, lk + i * 1024);
            glds16(gvt + i * 1024, lv + i * 1024);
        }
    };
    auto GT = [&](int ii) { return ii < ncache ? tlo + ii : 64 + (ii - ncache); };

    if (ntiles > 0) STAGE(0, GT(0));
    asm volatile("s_waitcnt vmcnt(0)" ::: "memory");
    __syncthreads();

    for (int ii = 0; ii < ntiles; ++ii) {
        const int cur = ii & 1;
        if (ii + 1 < ntiles) STAGE(cur ^ 1, GT(ii + 1));
        const int gt = GT(ii);
        const int t0 = gt * 64;

        // ---- Q @ K^T ----
        f4v sc[4];
#pragma unroll
        for (int ct = 0; ct < 4; ct++) sc[ct] = (f4v){0.f, 0.f, 0.f, 0.f};
#pragma unroll
        for (int ct = 0; ct < 4; ct++) {
#pragma unroll
            for (int ks = 0; ks < 4; ks++) {
                int r = ct * 16 + lm;
                s8v kf = *(const s8v*)(Ks[cur] + ((r * 256 + ks * 64 + lg * 16) ^ ((r & 7) << 4)));
                sc[ct] = __builtin_amdgcn_mfma_f32_16x16x32_bf16(qa[ks], kf, sc[ct], 0, 0, 0);
            }
        }
        if (gt < 64 && (t0 + 64 > cl)) {
#pragma unroll
            for (int ct = 0; ct < 4; ct++) {
                int p = t0 + ct * 16 + lm;
                if (p >= cl) { sc[ct][0] = -1e30f; sc[ct][1] = -1e30f; sc[ct][2] = -1e30f; sc[ct][3] = -1e30f; }
            }
        }

        // ---- online softmax ----
        float mnew[4], corr[4], rsum[4];
#pragma unroll
        for (int r = 0; r < 4; r++) {
            float mt = fmaxf(fmaxf(sc[0][r], sc[1][r]), fmaxf(sc[2][r], sc[3][r]));
#pragma unroll
            for (int off = 1; off < 16; off <<= 1) mt = fmaxf(mt, __shfl_xor(mt, off));
            float mn = fmaxf(m_run[r], mt);
            corr[r] = __expf(m_run[r] - mn);
            m_run[r] = mn;
            mnew[r] = mn;
            rsum[r] = 0.f;
        }
#pragma unroll
        for (int ct = 0; ct < 4; ct++) {
#pragma unroll
            for (int r = 0; r < 4; r++) {
                float pv = __expf(sc[ct][r] - mnew[r]);
                rsum[r] += pv;
                int row = lg * 4 + r;
                *(u16*)(Ps[wid] + ((row * 128 + (ct * 16 + lm) * 2) ^ ((row & 7) << 4))) = f2b(pv);
            }
        }
#pragma unroll
        for (int r = 0; r < 4; r++) {
            float rs = rsum[r];
#pragma unroll
            for (int off = 1; off < 16; off <<= 1) rs += __shfl_xor(rs, off);
            l_run[r] = l_run[r] * corr[r] + rs;
        }
#pragma unroll
        for (int dt = 0; dt < 8; dt++) {
#pragma unroll
            for (int r = 0; r < 4; r++) acc[dt][r] *= corr[r];
        }

        // ---- P A-frags ----
        s8v pa[2];
#pragma unroll
        for (int k2 = 0; k2 < 2; k2++)
            pa[k2] = *(const s8v*)(Ps[wid] + ((lm * 128 + k2 * 64 + lg * 16) ^ ((lm & 7) << 4)));

        // ---- P @ V ----
#pragma unroll
        for (int k2 = 0; k2 < 2; k2++) {
#pragma unroll
            for (int dt = 0; dt < 8; dt++) {
                i4v vv;
#pragma unroll
                for (int t = 0; t < 4; t++) {
                    int p = k2 * 16 + lg * 4 + t;
                    vv[t] = *(const int*)(Vs[cur] + p * 512 + ((((dt * 16 + lm) * 4)) ^ ((p & 31) << 4)));
                }
                union { i4v i; s8v s; } u; u.i = vv;
                acc[dt] = __builtin_amdgcn_mfma_f32_16x16x32_bf16(pa[k2], u.s, acc[dt], 0, 0, 0);
            }
        }

        asm volatile("s_waitcnt vmcnt(0)" ::: "memory");
        __syncthreads();
    }

#pragma unroll
    for (int dt = 0; dt < 8; dt++) {
#pragma unroll
        for (int r = 0; r < 4; r++) {
            int row = wid * 16 + lg * 4 + r;
            po[((size_t)bid * 64 + row) * 128 + dt * 16 + lm] = acc[dt][r];
        }
    }
    if (lm == 0) {
#pragma unroll
        for (int r = 0; r < 4; r++) {
            int row = wid * 16 + lg * 4 + r;
            mb[(size_t)bid * 64 + row] = m_run[r];
            lb[(size_t)bid * 64 + row] = l_run[r];
        }
    }
}

// ---------------------------------------------------------------------------
// Combine 4 splits.
// ---------------------------------------------------------------------------
__global__ __launch_bounds__(256) void fcomb_k(const float* __restrict__ po,
                                               const float* __restrict__ mb,
                                               const float* __restrict__ lb,
                                               u16* __restrict__ ob) {
    const int pid = blockIdx.x, t = threadIdx.x;
    const int row = t >> 2, dq = t & 3;
    const int half = pid & 1, h = (pid >> 1) & 31, b = pid >> 6;
    float m[4], l[4];
#pragma unroll
    for (int i = 0; i < 4; i++) {
        m[i] = mb[(size_t)(pid * 4 + i) * 64 + row];
        l[i] = lb[(size_t)(pid * 4 + i) * 64 + row];
    }
    float M = fmaxf(fmaxf(m[0], m[1]), fmaxf(m[2], m[3]));
    float w[4], L = 0.f;
#pragma unroll
    for (int i = 0; i < 4; i++) { w[i] = __expf(m[i] - M); L += w[i] * l[i]; }
    float invL = 1.0f / L;
    u16* dst = ob + ((size_t)(b * 128 + half * 64 + row) * 32 + h) * 128 + dq * 32;
#pragma unroll
    for (int j = 0; j < 8; j++) {
        f4v s = (f4v){0.f, 0.f, 0.f, 0.f};
#pragma unroll
        for (int i = 0; i < 4; i++) {
            f4v a = *(const f4v*)(po + ((size_t)(pid * 4 + i) * 64 + row) * 128 + dq * 32 + j * 4);
            s += w[i] * a;
        }
        ushort4 o;
        o.x = f2b(s[0] * invL); o.y = f2b(s[1] * invL);
        o.z = f2b(s[2] * invL); o.w = f2b(s[3] * invL);
        *(ushort4*)(dst + j * 4) = o;
    }
}

// ---------------------------------------------------------------------------
extern "C" void kernel_launch(void* const* d_in, const int* in_sizes, int n_in,
                              void* d_out, int out_size, void* d_ws, size_t ws_size,
                              hipStream_t stream) {
    const float* x   = (const float*)d_in[0];
    const float* Wq  = (const float*)d_in[1];
    const float* Wk  = (const float*)d_in[2];
    const float* Wv  = (const float*)d_in[3];
    const float* Wo  = (const float*)d_in[4];
    const float* qnw = (const float*)d_in[5];
    const float* knw = (const float*)d_in[6];
    const float* kc  = (const float*)d_in[7];
    const float* vc  = (const float*)d_in[8];
    const int* btab  = (const int*)d_in[9];
    const int* cseq  = (const int*)d_in[10];
    float* out = (float*)d_out;

    char* ws = (char*)d_ws;
    // layout (all regions' lifetimes verified disjoint):
    u16*   qb   = (u16*)(ws + 0);            // 4 MB
    u16*   kb   = (u16*)(ws + 4194304);      // 1 MB
    u16*   vb   = (u16*)(ws + 5242880);      // 1 MB
    u16*   ob   = (u16*)(ws + 6291456);      // 4 MB
    float* mbuf = (float*)(ws + 10485760);   // 256 KB
    float* lbuf = (float*)(ws + 10747904);   // 256 KB
    float* pA   = (float*)(ws + 11010048);   // 32 MB: Wq partials -> po -> Wo partials
    float* po   = (float*)(ws + 11010048);
    u16*   kb2  = (u16*)(ws + 44564480);     // 33 MB (written by cvtkv)
    u16*   vb2  = (u16*)(ws + 79167488);     // 33 MB (written by cvtkv)
    float* pK   = (float*)(ws + 79167488);   // 16 MB Wk partials (dead before vb2 write)
    float* pV   = (float*)(ws + 95944704);   // 16 MB Wv partials (dead before vb2 write)

    dim3 blk(256, 1, 1);
    fgemm_sk<0><<<dim3(32, 8, 4), blk, 0, stream>>>(x, Wq, pA, 512, 4096, 4096, 1024);
    fgemm_sk<0><<<dim3(8, 8, 8),  blk, 0, stream>>>(x, Wk, pK, 512, 1024, 4096, 512);
    fgemm_sk<0><<<dim3(8, 8, 8),  blk, 0, stream>>>(x, Wv, pV, 512, 1024, 4096, 512);
    nrope_k<<<dim3(4096, 1, 1), blk, 0, stream>>>(pA, qb, qnw, cseq, 32, SCALE_, 4, (size_t)512 * 4096);
    nrope_k<<<dim3(1024, 1, 1), blk, 0, stream>>>(pK, kb, knw, cseq, 8, 1.0f, 8, (size_t)512 * 1024);
    cvt_bf16k<<<dim3(512, 1, 1), blk, 0, stream>>>(pV, vb, 131072, 8, (size_t)512 * 1024);
    cvtkv_k<<<dim3(66, 8, 4), blk, 0, stream>>>(kc, vc, kb, vb, btab, cseq, kb2, vb2);
    fattn2_k<<<dim3(1024, 1, 1), blk, 0, stream>>>(qb, kb2, vb2, cseq, po, mbuf, lbuf);
    fcomb_k<<<dim3(256, 1, 1), blk, 0, stream>>>(po, mbuf, lbuf, ob);
    fgemm_sk<1><<<dim3(32, 8, 4), blk, 0, stream>>>(ob, Wo, pA, 512, 4096, 4096, 1024);
    red4_k<<<dim3(2048, 1, 1), blk, 0, stream>>>(pA, out, 2097152, (size_t)512 * 4096);
}